// Round 9
// baseline (27892.957 us; speedup 1.0000x reference)
//
#include <hip/hip_runtime.h>
#include <math.h>

// LSTM forward: T=1024, B=64, I=256, H=512 (4H=2048), fp32.
// Round 9: R8 structure UNCHANGED except amdgpu_waves_per_eu(2,2).
//   R7/R8 were scratch-bound: demand ~170 VGPR but allocator capped at 128
//   (4-wave/EU heuristic) and spilled ~90 floats/thread, reloaded every
//   step = 46 MB/step FETCH (measured 47 GB/dispatch). Pinning occupancy
//   to 2 waves/EU gives the 256-VGPR budget -> no spill.
// block = (rg: 8 rows) x (cg: 16 cells = 64 gate cols); 256 blocks x 512 thr.
// weights: 96 f32/thread in VGPRs; c LDS-resident; h chains through d_out;
// h exchange via sc0 sc1 bypass + explicit vmcnt drain (R6-verified);
// x_{t+1} pipelined; tid0-only spin.

#define TT      1024
#define BB      64
#define II      256
#define HH      512
#define G4H     2048
#define RPB     8
#define CPB     16
#define NCG     32
#define NRG     8
#define THREADS 512

__device__ __forceinline__ void coh_load2_f4(const float* p0, const float* p1,
                                             float4& a, float4& b) {
    asm volatile(
        "global_load_dwordx4 %0, %2, off sc0 sc1\n\t"
        "global_load_dwordx4 %1, %3, off sc0 sc1\n\t"
        "s_waitcnt vmcnt(0)"
        : "=&v"(a), "=&v"(b)
        : "v"(p0), "v"(p1)
        : "memory");
}
__device__ __forceinline__ void coh_store_f(float* p, float v) {
    asm volatile("global_store_dword %0, %1, off sc0 sc1"
                 :: "v"(p), "v"(v) : "memory");
}
__device__ __forceinline__ float fast_tanh(float v) {
    const float e = __expf(-2.0f * fabsf(v));
    const float r = (1.0f - e) / (1.0f + e);
    return v < 0.0f ? -r : r;
}

__global__ void init_ctr(unsigned int* ctr) { ctr[threadIdx.x] = 0; }

__global__ __launch_bounds__(THREADS)
__attribute__((amdgpu_waves_per_eu(2, 2)))
void lstm_persist(
    const float* __restrict__ x,    // [T][B][I]
    const float* __restrict__ Wi,   // [I][4H]
    const float* __restrict__ Wh,   // [H][4H]
    const float* __restrict__ bi,   // [4H]
    const float* __restrict__ bh,   // [4H]
    const float* __restrict__ h0,   // [B][H]
    const float* __restrict__ c0,   // [B][H]
    float* __restrict__ out,        // [T][B][H]
    unsigned int* __restrict__ ctr) // [NRG*32], pre-zeroed
{
    const int tid   = threadIdx.x;
    const int cg    = blockIdx.x & 31;
    const int rg    = blockIdx.x >> 5;
    const int row0  = rg * RPB;
    const int cell0 = cg * CPB;

    const int lane   = tid & 63;
    const int wv     = tid >> 6;
    const int colgrp = lane & 31;
    const int kc     = wv * 2 + (lane >> 5);   // k chunk 0..15

    const int bcA = colgrp, bcB = colgrp + 32;
    const int JA  = (bcA >> 4) * HH + cell0 + (bcA & 15);
    const int JB  = (bcB >> 4) * HH + cell0 + (bcB & 15);

    __shared__ float xbuf[RPB][II];        // 8 KB
    __shared__ float hbuf[RPB][HH];        // 16 KB
    __shared__ float red[8][RPB][68];      // 17.4 KB (padded)
    __shared__ float c_lds[RPB][CPB];      // 512 B, persistent

    // ---- one-time: weights -> VGPRs (2 cols x (16 x-k + 32 h-k)) ----
    float4 wxA[4], wxB[4], whA[8], whB[8];
    #pragma unroll
    for (int q = 0; q < 4; ++q) {
        float ta[4], tb[4];
        #pragma unroll
        for (int e = 0; e < 4; ++e) {
            const int k = kc * 16 + q * 4 + e;
            ta[e] = Wi[(size_t)k * G4H + JA];
            tb[e] = Wi[(size_t)k * G4H + JB];
        }
        wxA[q] = make_float4(ta[0], ta[1], ta[2], ta[3]);
        wxB[q] = make_float4(tb[0], tb[1], tb[2], tb[3]);
    }
    #pragma unroll
    for (int q = 0; q < 8; ++q) {
        float ta[4], tb[4];
        #pragma unroll
        for (int e = 0; e < 4; ++e) {
            const int k = kc * 32 + q * 4 + e;
            ta[e] = Wh[(size_t)k * G4H + JA];
            tb[e] = Wh[(size_t)k * G4H + JB];
        }
        whA[q] = make_float4(ta[0], ta[1], ta[2], ta[3]);
        whB[q] = make_float4(tb[0], tb[1], tb[2], tb[3]);
    }

    // update-role constants (threads 0..127): r = tid>>4, m = tid&15
    float b4[4];
    if (tid < RPB * CPB) {
        const int m = tid & 15;
        #pragma unroll
        for (int G = 0; G < 4; ++G)
            b4[G] = bi[G * HH + cell0 + m] + bh[G * HH + cell0 + m];
        c_lds[tid >> 4][m] = c0[(size_t)(row0 + (tid >> 4)) * HH + cell0 + m];
    }

    unsigned int* myctr = ctr + rg * 32;

    // ---- prologue: stage x_0 and h0 (conflict-free), x-partials for t=0 ----
    {
        const float4 xv = ((const float4*)(x + (size_t)(row0 + wv) * II))[lane];
        ((float4*)&xbuf[wv][0])[lane] = xv;
        const float4* hs = (const float4*)(h0 + (size_t)(row0 + wv) * HH);
        ((float4*)&hbuf[wv][0])[lane]      = hs[lane];
        ((float4*)&hbuf[wv][0])[lane + 64] = hs[lane + 64];
    }
    __syncthreads();

    float xaccA[RPB], xaccB[RPB];
    {
        const float4* xv4 = ((const float4*)&xbuf[0][0]) + kc * 4;
        #pragma unroll
        for (int r = 0; r < RPB; ++r) { xaccA[r] = 0.f; xaccB[r] = 0.f; }
        #pragma unroll
        for (int q = 0; q < 4; ++q) {
            const float4 wa = wxA[q], wb = wxB[q];
            #pragma unroll
            for (int r = 0; r < RPB; ++r) {
                const float4 a = xv4[r * 64 + q];
                xaccA[r] = fmaf(a.x, wa.x, xaccA[r]);
                xaccA[r] = fmaf(a.y, wa.y, xaccA[r]);
                xaccA[r] = fmaf(a.z, wa.z, xaccA[r]);
                xaccA[r] = fmaf(a.w, wa.w, xaccA[r]);
                xaccB[r] = fmaf(a.x, wb.x, xaccB[r]);
                xaccB[r] = fmaf(a.y, wb.y, xaccB[r]);
                xaccB[r] = fmaf(a.z, wb.z, xaccB[r]);
                xaccB[r] = fmaf(a.w, wb.w, xaccB[r]);
            }
        }
    }
    __syncthreads();

    for (int t = 0; t < TT; ++t) {
        const bool more = (t + 1 < TT);

        // ---- issue x_{t+1} load early (hidden under h-FMA) ----
        float4 xnext;
        if (more)
            xnext = ((const float4*)(x + ((size_t)(t + 1) * BB + row0 + wv) * II))[lane];

        // ---- h-FMA: acc starts from x-partials ----
        float accA[RPB], accB[RPB];
        #pragma unroll
        for (int r = 0; r < RPB; ++r) { accA[r] = xaccA[r]; accB[r] = xaccB[r]; }
        {
            const float4* hv4 = ((const float4*)&hbuf[0][0]) + kc * 8;
            #pragma unroll
            for (int q = 0; q < 8; ++q) {
                const float4 wa = whA[q], wb = whB[q];
                #pragma unroll
                for (int r = 0; r < RPB; ++r) {
                    const float4 a = hv4[r * 128 + q];
                    accA[r] = fmaf(a.x, wa.x, accA[r]);
                    accA[r] = fmaf(a.y, wa.y, accA[r]);
                    accA[r] = fmaf(a.z, wa.z, accA[r]);
                    accA[r] = fmaf(a.w, wa.w, accA[r]);
                    accB[r] = fmaf(a.x, wb.x, accB[r]);
                    accB[r] = fmaf(a.y, wb.y, accB[r]);
                    accB[r] = fmaf(a.z, wb.z, accB[r]);
                    accB[r] = fmaf(a.w, wb.w, accB[r]);
                }
            }
        }

        // ---- stage x_{t+1} (conflict-free: lane -> f4 #lane) ----
        if (more) ((float4*)&xbuf[wv][0])[lane] = xnext;

        // ---- wave reduce (pair kc, kc^1 at lane^32) + red writes ----
        #pragma unroll
        for (int r = 0; r < RPB; ++r) {
            accA[r] += __shfl_xor(accA[r], 32, 64);
            accB[r] += __shfl_xor(accB[r], 32, 64);
        }
        if (lane < 32) {
            #pragma unroll
            for (int r = 0; r < RPB; ++r) {
                red[wv][r][colgrp]      = accA[r];
                red[wv][r][colgrp + 32] = accB[r];
            }
        }
        __syncthreads();                       // S1

        // ---- assembly + cell update (threads 0..127) ----
        if (tid < RPB * CPB) {
            const int r = tid >> 4, m = tid & 15;
            float gate[4];
            #pragma unroll
            for (int G = 0; G < 4; ++G) {
                float s = b4[G];
                #pragma unroll
                for (int p = 0; p < 8; ++p) s += red[p][r][G * 16 + m];
                gate[G] = s;
            }
            const float ig = 1.0f / (1.0f + __expf(-gate[0]));
            const float fg = 1.0f / (1.0f + __expf(-gate[1]));
            const float gg = fast_tanh(gate[2]);
            const float og = 1.0f / (1.0f + __expf(-gate[3]));
            const float cn = fg * c_lds[r][m] + ig * gg;
            c_lds[r][m] = cn;
            const size_t idx = ((size_t)t * BB + row0 + r) * HH + cell0 + m;
            coh_store_f(out + idx, og * fast_tanh(cn));
        }

        // ---- drain h stores, then arrive ----
        asm volatile("s_waitcnt vmcnt(0) lgkmcnt(0)" ::: "memory");
        __syncthreads();                       // S2
        if (more) {
            // arrive FIRST (peers can observe while we compute x-partials)
            if (tid == 0)
                __hip_atomic_fetch_add(myctr, 1u, __ATOMIC_RELAXED,
                                       __HIP_MEMORY_SCOPE_AGENT);

            // ---- x-partials for t+1: fills the arrive->ready window ----
            {
                const float4* xv4 = ((const float4*)&xbuf[0][0]) + kc * 4;
                #pragma unroll
                for (int r = 0; r < RPB; ++r) { xaccA[r] = 0.f; xaccB[r] = 0.f; }
                #pragma unroll
                for (int q = 0; q < 4; ++q) {
                    const float4 wa = wxA[q], wb = wxB[q];
                    #pragma unroll
                    for (int r = 0; r < RPB; ++r) {
                        const float4 a = xv4[r * 64 + q];
                        xaccA[r] = fmaf(a.x, wa.x, xaccA[r]);
                        xaccA[r] = fmaf(a.y, wa.y, xaccA[r]);
                        xaccA[r] = fmaf(a.z, wa.z, xaccA[r]);
                        xaccA[r] = fmaf(a.w, wa.w, xaccA[r]);
                        xaccB[r] = fmaf(a.x, wb.x, xaccB[r]);
                        xaccB[r] = fmaf(a.y, wb.y, xaccB[r]);
                        xaccB[r] = fmaf(a.z, wb.z, xaccB[r]);
                        xaccB[r] = fmaf(a.w, wb.w, xaccB[r]);
                    }
                }
            }

            // ---- tid0-ONLY spin ----
            if (tid == 0) {
                const unsigned int target = 32u * (unsigned int)(t + 1);
                while (__hip_atomic_load(myctr, __ATOMIC_RELAXED,
                                         __HIP_MEMORY_SCOPE_AGENT) < target) {
                    __builtin_amdgcn_s_sleep(2);
                }
            }
            __syncthreads();                   // S3

            // ---- load h_t: wave wv loads its own row, conflict-free ----
            const float* hb = out + (size_t)t * BB * HH + (size_t)(row0 + wv) * HH;
            float4 ha, hb2;
            coh_load2_f4(hb + lane * 4, hb + 256 + lane * 4, ha, hb2);
            ((float4*)&hbuf[wv][0])[lane]      = ha;
            ((float4*)&hbuf[wv][0])[lane + 64] = hb2;
            __syncthreads();                   // S4
        }
    }
}

extern "C" void kernel_launch(void* const* d_in, const int* in_sizes, int n_in,
                              void* d_out, int out_size, void* d_ws, size_t ws_size,
                              hipStream_t stream) {
    const float* x  = (const float*)d_in[0];
    const float* Wi = (const float*)d_in[1];
    const float* Wh = (const float*)d_in[2];
    const float* bi = (const float*)d_in[3];
    const float* bh = (const float*)d_in[4];
    const float* h0 = (const float*)d_in[5];
    const float* c0 = (const float*)d_in[6];
    float* out = (float*)d_out;
    unsigned int* ctr = (unsigned int*)d_ws;   // 256 uints

    init_ctr<<<1, 256, 0, stream>>>(ctr);

    void* args[] = { (void*)&x, (void*)&Wi, (void*)&Wh, (void*)&bi,
                     (void*)&bh, (void*)&h0, (void*)&c0, (void*)&out,
                     (void*)&ctr };
    hipError_t e = hipLaunchCooperativeKernel((const void*)lstm_persist,
                                              dim3(NRG * NCG), dim3(THREADS),
                                              args, 0, stream);
    if (e != hipSuccess) {
        (void)hipGetLastError();
        lstm_persist<<<dim3(NRG * NCG), dim3(THREADS), 0, stream>>>(
            x, Wi, Wh, bi, bh, h0, c0, out, ctr);
    }
}

// Round 10
// 23169.130 us; speedup vs baseline: 1.2039x; 1.2039x over previous
//
#include <hip/hip_runtime.h>
#include <math.h>

// LSTM forward: T=1024, B=64, I=256, H=512 (4H=2048), fp32.
// Round 10: R8/R9 structure; register fix via __launch_bounds__(512, 2).
//   The 2nd launch_bounds arg (min waves per EU) is the documented knob that
//   sets the allocator's VGPR cap: 2 waves/EU -> 256 VGPRs. R7-R9 were
//   allocated 128 (default 4 waves/EU heuristic) and spilled ~40 floats,
//   whose per-step reloads were the 46+20 MB/step FETCH/WRITE scratch
//   traffic (= the whole 23 us/step). amdgpu_waves_per_eu attr (R9) was
//   silently ignored; the launch_bounds form is the one that works.
// block = (rg: 8 rows) x (cg: 16 cells = 64 gate cols); 256 blocks x 512 thr.
// weights: 96 f32/thread in VGPRs; c LDS-resident; h chains through d_out;
// h exchange via sc0 sc1 bypass + explicit vmcnt drain; x_{t+1} pipelined;
// tid0-only spin.

#define TT      1024
#define BB      64
#define II      256
#define HH      512
#define G4H     2048
#define RPB     8
#define CPB     16
#define NCG     32
#define NRG     8
#define THREADS 512

__device__ __forceinline__ void coh_load2_f4(const float* p0, const float* p1,
                                             float4& a, float4& b) {
    asm volatile(
        "global_load_dwordx4 %0, %2, off sc0 sc1\n\t"
        "global_load_dwordx4 %1, %3, off sc0 sc1\n\t"
        "s_waitcnt vmcnt(0)"
        : "=&v"(a), "=&v"(b)
        : "v"(p0), "v"(p1)
        : "memory");
}
__device__ __forceinline__ void coh_store_f(float* p, float v) {
    asm volatile("global_store_dword %0, %1, off sc0 sc1"
                 :: "v"(p), "v"(v) : "memory");
}
__device__ __forceinline__ float fast_tanh(float v) {
    const float e = __expf(-2.0f * fabsf(v));
    const float r = (1.0f - e) / (1.0f + e);
    return v < 0.0f ? -r : r;
}

__global__ void init_ctr(unsigned int* ctr) { ctr[threadIdx.x] = 0; }

__global__ __launch_bounds__(THREADS, 2) void lstm_persist(
    const float* __restrict__ x,    // [T][B][I]
    const float* __restrict__ Wi,   // [I][4H]
    const float* __restrict__ Wh,   // [H][4H]
    const float* __restrict__ bi,   // [4H]
    const float* __restrict__ bh,   // [4H]
    const float* __restrict__ h0,   // [B][H]
    const float* __restrict__ c0,   // [B][H]
    float* __restrict__ out,        // [T][B][H]
    unsigned int* __restrict__ ctr) // [NRG*32], pre-zeroed
{
    const int tid   = threadIdx.x;
    const int cg    = blockIdx.x & 31;
    const int rg    = blockIdx.x >> 5;
    const int row0  = rg * RPB;
    const int cell0 = cg * CPB;

    const int lane   = tid & 63;
    const int wv     = tid >> 6;
    const int colgrp = lane & 31;
    const int kc     = wv * 2 + (lane >> 5);   // k chunk 0..15

    const int bcA = colgrp, bcB = colgrp + 32;
    const int JA  = (bcA >> 4) * HH + cell0 + (bcA & 15);
    const int JB  = (bcB >> 4) * HH + cell0 + (bcB & 15);

    __shared__ float xbuf[RPB][II];        // 8 KB
    __shared__ float hbuf[RPB][HH];        // 16 KB
    __shared__ float red[8][RPB][68];      // 17.4 KB (padded)
    __shared__ float c_lds[RPB][CPB];      // 512 B, persistent

    // ---- one-time: weights -> VGPRs (2 cols x (16 x-k + 32 h-k)) ----
    float4 wxA[4], wxB[4], whA[8], whB[8];
    #pragma unroll
    for (int q = 0; q < 4; ++q) {
        float ta[4], tb[4];
        #pragma unroll
        for (int e = 0; e < 4; ++e) {
            const int k = kc * 16 + q * 4 + e;
            ta[e] = Wi[(size_t)k * G4H + JA];
            tb[e] = Wi[(size_t)k * G4H + JB];
        }
        wxA[q] = make_float4(ta[0], ta[1], ta[2], ta[3]);
        wxB[q] = make_float4(tb[0], tb[1], tb[2], tb[3]);
    }
    #pragma unroll
    for (int q = 0; q < 8; ++q) {
        float ta[4], tb[4];
        #pragma unroll
        for (int e = 0; e < 4; ++e) {
            const int k = kc * 32 + q * 4 + e;
            ta[e] = Wh[(size_t)k * G4H + JA];
            tb[e] = Wh[(size_t)k * G4H + JB];
        }
        whA[q] = make_float4(ta[0], ta[1], ta[2], ta[3]);
        whB[q] = make_float4(tb[0], tb[1], tb[2], tb[3]);
    }

    // update-role constants (threads 0..127): r = tid>>4, m = tid&15
    float b4[4];
    if (tid < RPB * CPB) {
        const int m = tid & 15;
        #pragma unroll
        for (int G = 0; G < 4; ++G)
            b4[G] = bi[G * HH + cell0 + m] + bh[G * HH + cell0 + m];
        c_lds[tid >> 4][m] = c0[(size_t)(row0 + (tid >> 4)) * HH + cell0 + m];
    }

    unsigned int* myctr = ctr + rg * 32;

    // ---- prologue: stage x_0 and h0 (conflict-free), x-partials for t=0 ----
    {
        const float4 xv = ((const float4*)(x + (size_t)(row0 + wv) * II))[lane];
        ((float4*)&xbuf[wv][0])[lane] = xv;
        const float4* hs = (const float4*)(h0 + (size_t)(row0 + wv) * HH);
        ((float4*)&hbuf[wv][0])[lane]      = hs[lane];
        ((float4*)&hbuf[wv][0])[lane + 64] = hs[lane + 64];
    }
    __syncthreads();

    float xaccA[RPB], xaccB[RPB];
    {
        const float4* xv4 = ((const float4*)&xbuf[0][0]) + kc * 4;
        #pragma unroll
        for (int r = 0; r < RPB; ++r) { xaccA[r] = 0.f; xaccB[r] = 0.f; }
        #pragma unroll
        for (int q = 0; q < 4; ++q) {
            const float4 wa = wxA[q], wb = wxB[q];
            #pragma unroll
            for (int r = 0; r < RPB; ++r) {
                const float4 a = xv4[r * 64 + q];
                xaccA[r] = fmaf(a.x, wa.x, xaccA[r]);
                xaccA[r] = fmaf(a.y, wa.y, xaccA[r]);
                xaccA[r] = fmaf(a.z, wa.z, xaccA[r]);
                xaccA[r] = fmaf(a.w, wa.w, xaccA[r]);
                xaccB[r] = fmaf(a.x, wb.x, xaccB[r]);
                xaccB[r] = fmaf(a.y, wb.y, xaccB[r]);
                xaccB[r] = fmaf(a.z, wb.z, xaccB[r]);
                xaccB[r] = fmaf(a.w, wb.w, xaccB[r]);
            }
        }
    }
    __syncthreads();

    for (int t = 0; t < TT; ++t) {
        const bool more = (t + 1 < TT);

        // ---- issue x_{t+1} load early (hidden under h-FMA) ----
        float4 xnext;
        if (more)
            xnext = ((const float4*)(x + ((size_t)(t + 1) * BB + row0 + wv) * II))[lane];

        // ---- h-FMA: acc starts from x-partials ----
        float accA[RPB], accB[RPB];
        #pragma unroll
        for (int r = 0; r < RPB; ++r) { accA[r] = xaccA[r]; accB[r] = xaccB[r]; }
        {
            const float4* hv4 = ((const float4*)&hbuf[0][0]) + kc * 8;
            #pragma unroll
            for (int q = 0; q < 8; ++q) {
                const float4 wa = whA[q], wb = whB[q];
                #pragma unroll
                for (int r = 0; r < RPB; ++r) {
                    const float4 a = hv4[r * 128 + q];
                    accA[r] = fmaf(a.x, wa.x, accA[r]);
                    accA[r] = fmaf(a.y, wa.y, accA[r]);
                    accA[r] = fmaf(a.z, wa.z, accA[r]);
                    accA[r] = fmaf(a.w, wa.w, accA[r]);
                    accB[r] = fmaf(a.x, wb.x, accB[r]);
                    accB[r] = fmaf(a.y, wb.y, accB[r]);
                    accB[r] = fmaf(a.z, wb.z, accB[r]);
                    accB[r] = fmaf(a.w, wb.w, accB[r]);
                }
            }
        }

        // ---- stage x_{t+1} (conflict-free: lane -> f4 #lane) ----
        if (more) ((float4*)&xbuf[wv][0])[lane] = xnext;

        // ---- wave reduce (pair kc, kc^1 at lane^32) + red writes ----
        #pragma unroll
        for (int r = 0; r < RPB; ++r) {
            accA[r] += __shfl_xor(accA[r], 32, 64);
            accB[r] += __shfl_xor(accB[r], 32, 64);
        }
        if (lane < 32) {
            #pragma unroll
            for (int r = 0; r < RPB; ++r) {
                red[wv][r][colgrp]      = accA[r];
                red[wv][r][colgrp + 32] = accB[r];
            }
        }
        __syncthreads();                       // S1

        // ---- assembly + cell update (threads 0..127) ----
        if (tid < RPB * CPB) {
            const int r = tid >> 4, m = tid & 15;
            float gate[4];
            #pragma unroll
            for (int G = 0; G < 4; ++G) {
                float s = b4[G];
                #pragma unroll
                for (int p = 0; p < 8; ++p) s += red[p][r][G * 16 + m];
                gate[G] = s;
            }
            const float ig = 1.0f / (1.0f + __expf(-gate[0]));
            const float fg = 1.0f / (1.0f + __expf(-gate[1]));
            const float gg = fast_tanh(gate[2]);
            const float og = 1.0f / (1.0f + __expf(-gate[3]));
            const float cn = fg * c_lds[r][m] + ig * gg;
            c_lds[r][m] = cn;
            const size_t idx = ((size_t)t * BB + row0 + r) * HH + cell0 + m;
            coh_store_f(out + idx, og * fast_tanh(cn));
        }

        // ---- drain h stores, then arrive ----
        asm volatile("s_waitcnt vmcnt(0) lgkmcnt(0)" ::: "memory");
        __syncthreads();                       // S2
        if (more) {
            // arrive FIRST (peers can observe while we compute x-partials)
            if (tid == 0)
                __hip_atomic_fetch_add(myctr, 1u, __ATOMIC_RELAXED,
                                       __HIP_MEMORY_SCOPE_AGENT);

            // ---- x-partials for t+1: fills the arrive->ready window ----
            {
                const float4* xv4 = ((const float4*)&xbuf[0][0]) + kc * 4;
                #pragma unroll
                for (int r = 0; r < RPB; ++r) { xaccA[r] = 0.f; xaccB[r] = 0.f; }
                #pragma unroll
                for (int q = 0; q < 4; ++q) {
                    const float4 wa = wxA[q], wb = wxB[q];
                    #pragma unroll
                    for (int r = 0; r < RPB; ++r) {
                        const float4 a = xv4[r * 64 + q];
                        xaccA[r] = fmaf(a.x, wa.x, xaccA[r]);
                        xaccA[r] = fmaf(a.y, wa.y, xaccA[r]);
                        xaccA[r] = fmaf(a.z, wa.z, xaccA[r]);
                        xaccA[r] = fmaf(a.w, wa.w, xaccA[r]);
                        xaccB[r] = fmaf(a.x, wb.x, xaccB[r]);
                        xaccB[r] = fmaf(a.y, wb.y, xaccB[r]);
                        xaccB[r] = fmaf(a.z, wb.z, xaccB[r]);
                        xaccB[r] = fmaf(a.w, wb.w, xaccB[r]);
                    }
                }
            }

            // ---- tid0-ONLY spin ----
            if (tid == 0) {
                const unsigned int target = 32u * (unsigned int)(t + 1);
                while (__hip_atomic_load(myctr, __ATOMIC_RELAXED,
                                         __HIP_MEMORY_SCOPE_AGENT) < target) {
                    __builtin_amdgcn_s_sleep(2);
                }
            }
            __syncthreads();                   // S3

            // ---- load h_t: wave wv loads its own row, conflict-free ----
            const float* hb = out + (size_t)t * BB * HH + (size_t)(row0 + wv) * HH;
            float4 ha, hb2;
            coh_load2_f4(hb + lane * 4, hb + 256 + lane * 4, ha, hb2);
            ((float4*)&hbuf[wv][0])[lane]      = ha;
            ((float4*)&hbuf[wv][0])[lane + 64] = hb2;
            __syncthreads();                   // S4
        }
    }
}

extern "C" void kernel_launch(void* const* d_in, const int* in_sizes, int n_in,
                              void* d_out, int out_size, void* d_ws, size_t ws_size,
                              hipStream_t stream) {
    const float* x  = (const float*)d_in[0];
    const float* Wi = (const float*)d_in[1];
    const float* Wh = (const float*)d_in[2];
    const float* bi = (const float*)d_in[3];
    const float* bh = (const float*)d_in[4];
    const float* h0 = (const float*)d_in[5];
    const float* c0 = (const float*)d_in[6];
    float* out = (float*)d_out;
    unsigned int* ctr = (unsigned int*)d_ws;   // 256 uints

    init_ctr<<<1, 256, 0, stream>>>(ctr);

    void* args[] = { (void*)&x, (void*)&Wi, (void*)&Wh, (void*)&bi,
                     (void*)&bh, (void*)&h0, (void*)&c0, (void*)&out,
                     (void*)&ctr };
    hipError_t e = hipLaunchCooperativeKernel((const void*)lstm_persist,
                                              dim3(NRG * NCG), dim3(THREADS),
                                              args, 0, stream);
    if (e != hipSuccess) {
        (void)hipGetLastError();
        lstm_persist<<<dim3(NRG * NCG), dim3(THREADS), 0, stream>>>(
            x, Wi, Wh, bi, bh, h0, c0, out, ctr);
    }
}

// Round 11
// 14940.288 us; speedup vs baseline: 1.8670x; 1.5508x over previous
//
#include <hip/hip_runtime.h>
#include <math.h>

// LSTM forward: T=1024, B=64, I=256, H=512 (4H=2048), fp32.
// Round 11: weights LDS-RESIDENT (loaded once), tiny register footprint.
//   R7-R10 lesson: compiler caps VGPRs at 128 -> per-thread register weights
//   spill to scratch (33MB footprint -> L2 thrash -> 46+20 MB/step HBM).
//   Here per-thread state ~60 VGPRs by construction; weights never re-read.
// block = (rg: 16 rows) x (cg: 8 cells = 32 gate cols); 4x64 = 256 blocks.
// LDS: pack[512 slices x 13 f4] (stride-13 -> conflict-free per-lane b128),
//      act[16][768] linear (k striped k=4kq+64n -> wave act read = one
//      contiguous 128B line, 8-way col broadcast), red, c. Total 160.5 KB.
// thread = (col = p*8+c2, kq = hi*8+kq3); acc[16 rows]; 768 FMA/thread/step.
// Sync: R6-verified sc0/sc1 IF$ exchange + explicit vmcnt drain + tid0 spin;
// x-stripes (n<4) computed in the arrive->spin window (R8 pipeline).

#define TT      1024
#define BB      64
#define II      256
#define HH      512
#define G4H     2048
#define RPB     16
#define COLS    32
#define NRG     4
#define NCG     64
#define THREADS 512
#define PF4     13      // pack slice stride in float4 units (12 used)

__device__ __forceinline__ void coh_load4_f4(const float* p0, const float* p1,
                                             const float* p2, const float* p3,
                                             float4& a, float4& b,
                                             float4& c, float4& d) {
    asm volatile(
        "global_load_dwordx4 %0, %4, off sc0 sc1\n\t"
        "global_load_dwordx4 %1, %5, off sc0 sc1\n\t"
        "global_load_dwordx4 %2, %6, off sc0 sc1\n\t"
        "global_load_dwordx4 %3, %7, off sc0 sc1\n\t"
        "s_waitcnt vmcnt(0)"
        : "=&v"(a), "=&v"(b), "=&v"(c), "=&v"(d)
        : "v"(p0), "v"(p1), "v"(p2), "v"(p3)
        : "memory");
}
__device__ __forceinline__ void coh_store_f(float* p, float v) {
    asm volatile("global_store_dword %0, %1, off sc0 sc1"
                 :: "v"(p), "v"(v) : "memory");
}
__device__ __forceinline__ float fast_tanh(float v) {
    const float e = __expf(-2.0f * fabsf(v));
    const float r = (1.0f - e) / (1.0f + e);
    return v < 0.0f ? -r : r;
}
__device__ __forceinline__ float sigm(float v) {
    return 1.0f / (1.0f + __expf(-v));
}

__global__ void init_ctr(unsigned int* ctr) { ctr[threadIdx.x] = 0; }

__global__ __launch_bounds__(THREADS) void lstm_persist(
    const float* __restrict__ x,    // [T][B][I]
    const float* __restrict__ Wi,   // [I][4H]
    const float* __restrict__ Wh,   // [H][4H]
    const float* __restrict__ bi,   // [4H]
    const float* __restrict__ bh,   // [4H]
    const float* __restrict__ h0,   // [B][H]
    const float* __restrict__ c0,   // [B][H]
    float* __restrict__ out,        // [T][B][H]
    unsigned int* __restrict__ ctr) // [NRG*32], pre-zeroed
{
    const int tid   = threadIdx.x;
    const int cg    = blockIdx.x & 63;        // cell group (8 cells)
    const int rg    = blockIdx.x >> 6;        // row group (16 rows)
    const int row0  = rg * RPB;
    const int cell0 = cg * 8;

    const int wv   = tid >> 6;
    const int lane = tid & 63;
    const int p    = wv >> 1;                 // col-group pair 0..3
    const int hi   = wv & 1;                  // kq high bit
    const int c2   = lane & 7;
    const int kq3  = lane >> 3;               // 0..7
    const int col  = p * 8 + c2;              // block-local gate col 0..31
    const int kq   = hi * 8 + kq3;            // 0..15; k = 4*kq + 64*n

    __shared__ float pack[THREADS * PF4 * 4]; // 106,496 B
    __shared__ float act[RPB][768];           //  49,152 B ([r][x|h] striped k)
    __shared__ float red[2][COLS][17];        //   4,352 B
    __shared__ float c_lds[RPB][8];           //     512 B
    // total 160,512 B  (<= 160 KiB)

    // ---- one-time: gather weights into pack (per-thread 12xf4 slices) ----
    for (int i = 0; i < 48; ++i) {
        const int s = tid + THREADS * i;      // 0..24575
        const int k = s >> 5, c = s & 31;
        const int J = (c >> 3) * HH + cell0 + (c & 7);
        const float v = (k < II) ? Wi[(size_t)k * G4H + J]
                                 : Wh[(size_t)(k - II) * G4H + J];
        const int n  = k >> 6;                // stripe 0..11
        const int kk = (k & 63) >> 2;         // kq of this element
        const int e  = k & 3;
        const int slot = ((c >> 3) * 2 + (kk >> 3)) * 64 + ((c & 7) + 8 * (kk & 7));
        pack[slot * (PF4 * 4) + n * 4 + e] = v;
    }

    // ---- update-role constants (threads 0..127): r = tid>>3, m8 = tid&7 ----
    float b4[4];
    if (tid < 128) {
        const int r = tid >> 3, m8 = tid & 7;
        #pragma unroll
        for (int g = 0; g < 4; ++g)
            b4[g] = bi[g * HH + cell0 + m8] + bh[g * HH + cell0 + m8];
        c_lds[r][m8] = c0[(size_t)(row0 + r) * HH + cell0 + m8];
    }

    // ---- prologue: stage x_0 and h0 (coalesced, plain loads) ----
    {
        #pragma unroll
        for (int i = 0; i < 2; ++i) {
            const int s = tid + THREADS * i, r = s >> 6, c4 = s & 63;
            const float4 v = *(const float4*)(x + (size_t)(row0 + r) * II + 4 * c4);
            ((float4*)&act[0][0])[r * 192 + c4] = v;
        }
        #pragma unroll
        for (int i = 0; i < 4; ++i) {
            const int s = tid + THREADS * i, r = s >> 7, c4 = s & 127;
            const float4 v = *(const float4*)(h0 + (size_t)(row0 + r) * HH + 4 * c4);
            ((float4*)&act[0][0])[r * 192 + 64 + c4] = v;
        }
    }
    __syncthreads();

    const float4* packv = (const float4*)pack;
    const float4* actv  = (const float4*)&act[0][0];
    const int wbase = tid * PF4;

    // ---- x-partials for t=0 (stripes n=0..3 are exactly k<256) ----
    float acc[RPB];
    #pragma unroll
    for (int r = 0; r < RPB; ++r) acc[r] = 0.f;
    #pragma unroll
    for (int n = 0; n < 4; ++n) {
        const float4 w = packv[wbase + n];
        #pragma unroll
        for (int r = 0; r < RPB; ++r) {
            const float4 a = actv[r * 192 + kq + 16 * n];
            acc[r] = fmaf(a.x, w.x, acc[r]);
            acc[r] = fmaf(a.y, w.y, acc[r]);
            acc[r] = fmaf(a.z, w.z, acc[r]);
            acc[r] = fmaf(a.w, w.w, acc[r]);
        }
    }

    unsigned int* myctr = ctr + rg * 32;

    for (int t = 0; t < TT; ++t) {
        const bool more = (t + 1 < TT);

        // ---- issue x_{t+1} loads early (plain; hidden under h-FMA) ----
        float4 xr0, xr1;
        if (more) {
            const int s0 = tid,          r0 = s0 >> 6, a0 = s0 & 63;
            const int s1 = tid + 512,    r1 = s1 >> 6, a1 = s1 & 63;
            xr0 = *(const float4*)(x + ((size_t)(t + 1) * BB + row0 + r0) * II + 4 * a0);
            xr1 = *(const float4*)(x + ((size_t)(t + 1) * BB + row0 + r1) * II + 4 * a1);
        }

        // ---- h-FMA: stripes n=4..11 (k>=256), acc carries x-partials ----
        #pragma unroll
        for (int n = 4; n < 12; ++n) {
            const float4 w = packv[wbase + n];
            #pragma unroll
            for (int r = 0; r < RPB; ++r) {
                const float4 a = actv[r * 192 + kq + 16 * n];
                acc[r] = fmaf(a.x, w.x, acc[r]);
                acc[r] = fmaf(a.y, w.y, acc[r]);
                acc[r] = fmaf(a.z, w.z, acc[r]);
                acc[r] = fmaf(a.w, w.w, acc[r]);
            }
        }

        // ---- in-wave reduce over kq3 (lane bits 3..5) ----
        #pragma unroll
        for (int r = 0; r < RPB; ++r) {
            acc[r] += __shfl_xor(acc[r], 8, 64);
            acc[r] += __shfl_xor(acc[r], 16, 64);
            acc[r] += __shfl_xor(acc[r], 32, 64);
        }
        if (kq3 == 0) {
            #pragma unroll
            for (int r = 0; r < RPB; ++r) red[hi][col][r] = acc[r];
        }

        // ---- stage x_{t+1} into act x-region (free: x_t already consumed) ----
        if (more) {
            const int s0 = tid,       r0 = s0 >> 6, a0 = s0 & 63;
            const int s1 = tid + 512, r1 = s1 >> 6, a1 = s1 & 63;
            ((float4*)&act[0][0])[r0 * 192 + a0] = xr0;
            ((float4*)&act[0][0])[r1 * 192 + a1] = xr1;
        }
        __syncthreads();                         // S1

        // ---- cell update: 16 rows x 8 cells = 128 threads ----
        if (tid < 128) {
            const int r = tid >> 3, m8 = tid & 7;
            float g4[4];
            #pragma unroll
            for (int g = 0; g < 4; ++g)
                g4[g] = red[0][g * 8 + m8][r] + red[1][g * 8 + m8][r] + b4[g];
            const float ig = sigm(g4[0]);
            const float fg = sigm(g4[1]);
            const float gg = fast_tanh(g4[2]);
            const float og = sigm(g4[3]);
            const float cn = fg * c_lds[r][m8] + ig * gg;
            c_lds[r][m8] = cn;
            coh_store_f(out + ((size_t)t * BB + row0 + r) * HH + cell0 + m8,
                        og * fast_tanh(cn));
        }

        // ---- drain h stores, then arrive ----
        asm volatile("s_waitcnt vmcnt(0) lgkmcnt(0)" ::: "memory");
        __syncthreads();                         // S2
        if (more) {
            if (tid == 0)
                __hip_atomic_fetch_add(myctr, 1u, __ATOMIC_RELAXED,
                                       __HIP_MEMORY_SCOPE_AGENT);

            // ---- window: x-partials for t+1 (fills arrive->ready skew) ----
            #pragma unroll
            for (int r = 0; r < RPB; ++r) acc[r] = 0.f;
            #pragma unroll
            for (int n = 0; n < 4; ++n) {
                const float4 w = packv[wbase + n];
                #pragma unroll
                for (int r = 0; r < RPB; ++r) {
                    const float4 a = actv[r * 192 + kq + 16 * n];
                    acc[r] = fmaf(a.x, w.x, acc[r]);
                    acc[r] = fmaf(a.y, w.y, acc[r]);
                    acc[r] = fmaf(a.z, w.z, acc[r]);
                    acc[r] = fmaf(a.w, w.w, acc[r]);
                }
            }

            // ---- tid0-only spin (R6-proven) ----
            if (tid == 0) {
                const unsigned int target = 64u * (unsigned int)(t + 1);
                while (__hip_atomic_load(myctr, __ATOMIC_RELAXED,
                                         __HIP_MEMORY_SCOPE_AGENT) < target) {
                    __builtin_amdgcn_s_sleep(2);
                }
            }
            __syncthreads();                     // S3

            // ---- load h_t (coherent) -> act h-region, coalesced ----
            {
                const float* hb = out + (size_t)t * BB * HH;
                const int s0 = tid,        r0 = s0 >> 7, a0 = s0 & 127;
                const int s1 = tid + 512,  r1 = s1 >> 7, a1 = s1 & 127;
                const int s2 = tid + 1024, r2 = s2 >> 7, a2 = s2 & 127;
                const int s3 = tid + 1536, r3 = s3 >> 7, a3 = s3 & 127;
                float4 v0, v1, v2, v3;
                coh_load4_f4(hb + (size_t)(row0 + r0) * HH + 4 * a0,
                             hb + (size_t)(row0 + r1) * HH + 4 * a1,
                             hb + (size_t)(row0 + r2) * HH + 4 * a2,
                             hb + (size_t)(row0 + r3) * HH + 4 * a3,
                             v0, v1, v2, v3);
                ((float4*)&act[0][0])[r0 * 192 + 64 + a0] = v0;
                ((float4*)&act[0][0])[r1 * 192 + 64 + a1] = v1;
                ((float4*)&act[0][0])[r2 * 192 + 64 + a2] = v2;
                ((float4*)&act[0][0])[r3 * 192 + 64 + a3] = v3;
            }
            __syncthreads();                     // S4
        }
    }
}

extern "C" void kernel_launch(void* const* d_in, const int* in_sizes, int n_in,
                              void* d_out, int out_size, void* d_ws, size_t ws_size,
                              hipStream_t stream) {
    const float* x  = (const float*)d_in[0];
    const float* Wi = (const float*)d_in[1];
    const float* Wh = (const float*)d_in[2];
    const float* bi = (const float*)d_in[3];
    const float* bh = (const float*)d_in[4];
    const float* h0 = (const float*)d_in[5];
    const float* c0 = (const float*)d_in[6];
    float* out = (float*)d_out;
    unsigned int* ctr = (unsigned int*)d_ws;   // 256 uints

    init_ctr<<<1, 256, 0, stream>>>(ctr);

    void* args[] = { (void*)&x, (void*)&Wi, (void*)&Wh, (void*)&bi,
                     (void*)&bh, (void*)&h0, (void*)&c0, (void*)&out,
                     (void*)&ctr };
    hipError_t e = hipLaunchCooperativeKernel((const void*)lstm_persist,
                                              dim3(NRG * NCG), dim3(THREADS),
                                              args, 0, stream);
    if (e != hipSuccess) {
        (void)hipGetLastError();
        // 256 blocks at 1 block/CU (LDS-bound) co-reside with plain dispatch
        lstm_persist<<<dim3(NRG * NCG), dim3(THREADS), 0, stream>>>(
            x, Wi, Wh, bi, bh, h0, c0, out, ctr);
    }
}

// Round 12
// 7064.316 us; speedup vs baseline: 3.9484x; 2.1149x over previous
//
#include <hip/hip_runtime.h>
#include <math.h>

// LSTM forward: T=1024, B=64, I=256, H=512 (4H=2048), fp32.
// Round 12: R11 (LDS-resident weights) with per-thread state halved.
//   Register ledger: cap is 128 VGPRs (immovable; R7-R11). R11's acc[16]
//   demand ~140 -> 35 dw/thread/step spill (17.4 MB/step WRITE). Here:
//   thread = (col 0..31) x (row-half rh) x (kq8 0..7): acc[8], ~75 VGPR
//   demand -> zero spill by construction.
//   * weights: LDS pack, 256 shared slices (col,kq8) x 24 f4, stride 25 f4
//     (25 mod 8 = 1 -> balanced bank-quads on per-lane ds_read_b128)
//   * act[16][768] linear; k striped k=4*kq8+32*n -> wave act read = one
//     contiguous 128B line (8-way broadcast, conflict-free)
//   * reduction: 3x shfl_xor over kq8 only; rh threads own disjoint rows
//     -> red[32][17] written once, no cross-wave adds
//   * R6/R11-verified sync: sc0 sc1 IF$ exchange, explicit vmcnt drain,
//     tid0-only spin; x_{t+1} partials computed in the arrive->spin window
// block = (rg: 16 rows) x (cg: 8 cells); 4 x 64 = 256 blocks x 512 thr.

#define TT      1024
#define BB      64
#define II      256
#define HH      512
#define G4H     2048
#define RPB     16
#define COLS    32
#define NRG     4
#define NCG     64
#define THREADS 512
#define PF4     25      // pack slice stride in float4 units (24 used)

__device__ __forceinline__ void coh_load4_f4(const float* p0, const float* p1,
                                             const float* p2, const float* p3,
                                             float4& a, float4& b,
                                             float4& c, float4& d) {
    asm volatile(
        "global_load_dwordx4 %0, %4, off sc0 sc1\n\t"
        "global_load_dwordx4 %1, %5, off sc0 sc1\n\t"
        "global_load_dwordx4 %2, %6, off sc0 sc1\n\t"
        "global_load_dwordx4 %3, %7, off sc0 sc1\n\t"
        "s_waitcnt vmcnt(0)"
        : "=&v"(a), "=&v"(b), "=&v"(c), "=&v"(d)
        : "v"(p0), "v"(p1), "v"(p2), "v"(p3)
        : "memory");
}
__device__ __forceinline__ void coh_store_f(float* p, float v) {
    asm volatile("global_store_dword %0, %1, off sc0 sc1"
                 :: "v"(p), "v"(v) : "memory");
}
__device__ __forceinline__ float fast_tanh(float v) {
    const float e = __expf(-2.0f * fabsf(v));
    const float r = (1.0f - e) / (1.0f + e);
    return v < 0.0f ? -r : r;
}
__device__ __forceinline__ float sigm(float v) {
    return 1.0f / (1.0f + __expf(-v));
}

__global__ void init_ctr(unsigned int* ctr) { ctr[threadIdx.x] = 0; }

__global__ __launch_bounds__(THREADS) void lstm_persist(
    const float* __restrict__ x,    // [T][B][I]
    const float* __restrict__ Wi,   // [I][4H]
    const float* __restrict__ Wh,   // [H][4H]
    const float* __restrict__ bi,   // [4H]
    const float* __restrict__ bh,   // [4H]
    const float* __restrict__ h0,   // [B][H]
    const float* __restrict__ c0,   // [B][H]
    float* __restrict__ out,        // [T][B][H]
    unsigned int* __restrict__ ctr) // [NRG*32], pre-zeroed
{
    const int tid   = threadIdx.x;
    const int cg    = blockIdx.x & 63;        // cell group (8 cells)
    const int rg    = blockIdx.x >> 6;        // row group (16 rows)
    const int row0  = rg * RPB;
    const int cell0 = cg * 8;

    const int wv    = tid >> 6;
    const int lane  = tid & 63;
    const int kq8   = lane & 7;               // k-quad low (k = 4*kq8 + 32*n)
    const int c3    = lane >> 3;              // col low 3 bits
    const int c2    = wv >> 1;                // col high 2 bits = gate
    const int rh    = wv & 1;                 // row half
    const int col   = c2 * 8 + c3;            // block-local gate col 0..31
    const int rbase = rh * 8;
    const int slice = col * 8 + kq8;          // 0..255 (= c2*64 + lane)
    const int wbase = slice * PF4;            // pack base, f4 units

    __shared__ float pack[256 * PF4 * 4];     // 102,400 B
    __shared__ float act[RPB][768];           //  49,152 B
    __shared__ float red[COLS][17];           //   2,176 B
    __shared__ float c_lds[RPB][8];           //     512 B  (total 154,240 B)

    // ---- one-time: gather weights into pack ----
    for (int i = 0; i < 48; ++i) {
        const int s   = tid + THREADS * i;    // 0..24575
        const int sl  = s / 96;
        const int rem = s - sl * 96;
        const int n   = rem >> 2, e = rem & 3;
        const int cw  = sl >> 3, kq = sl & 7;
        const int k   = 4 * kq + 32 * n + e;
        const int J   = (cw >> 3) * HH + cell0 + (cw & 7);
        const float v = (k < II) ? Wi[(size_t)k * G4H + J]
                                 : Wh[(size_t)(k - II) * G4H + J];
        pack[sl * (PF4 * 4) + n * 4 + e] = v;
    }

    // ---- update-role constants (threads 0..127): r = tid>>3, m8 = tid&7 ----
    float b4[4];
    if (tid < 128) {
        const int r = tid >> 3, m8 = tid & 7;
        #pragma unroll
        for (int g = 0; g < 4; ++g)
            b4[g] = bi[g * HH + cell0 + m8] + bh[g * HH + cell0 + m8];
        c_lds[r][m8] = c0[(size_t)(row0 + r) * HH + cell0 + m8];
    }

    // ---- prologue: stage x_0 and h0 (coalesced, plain loads) ----
    {
        #pragma unroll
        for (int i = 0; i < 2; ++i) {
            const int s = tid + THREADS * i, r = s >> 6, c4 = s & 63;
            const float4 v = *(const float4*)(x + (size_t)(row0 + r) * II + 4 * c4);
            ((float4*)&act[0][0])[r * 192 + c4] = v;
        }
        #pragma unroll
        for (int i = 0; i < 4; ++i) {
            const int s = tid + THREADS * i, r = s >> 7, c4 = s & 127;
            const float4 v = *(const float4*)(h0 + (size_t)(row0 + r) * HH + 4 * c4);
            ((float4*)&act[0][0])[r * 192 + 64 + c4] = v;
        }
    }
    __syncthreads();

    const float4* packv = (const float4*)pack;
    const float4* actv  = (const float4*)&act[0][0];

    // ---- x-partials for t=0 (stripes n=0..7 are exactly k<256) ----
    float acc[8];
    #pragma unroll
    for (int rr = 0; rr < 8; ++rr) acc[rr] = 0.f;
    #pragma unroll 2
    for (int n = 0; n < 8; ++n) {
        const float4 w = packv[wbase + n];
        const int ab = kq8 + 8 * n;
        #pragma unroll
        for (int rr = 0; rr < 8; ++rr) {
            const float4 a = actv[(rbase + rr) * 192 + ab];
            acc[rr] = fmaf(a.x, w.x, acc[rr]);
            acc[rr] = fmaf(a.y, w.y, acc[rr]);
            acc[rr] = fmaf(a.z, w.z, acc[rr]);
            acc[rr] = fmaf(a.w, w.w, acc[rr]);
        }
    }

    unsigned int* myctr = ctr + rg * 32;

    for (int t = 0; t < TT; ++t) {
        const bool more = (t + 1 < TT);

        // ---- issue x_{t+1} loads early (plain; hidden under h-FMA) ----
        float4 xr0, xr1;
        if (more) {
            const int s0 = tid,       r0 = s0 >> 6, a0 = s0 & 63;
            const int s1 = tid + 512, r1 = s1 >> 6, a1 = s1 & 63;
            xr0 = *(const float4*)(x + ((size_t)(t + 1) * BB + row0 + r0) * II + 4 * a0);
            xr1 = *(const float4*)(x + ((size_t)(t + 1) * BB + row0 + r1) * II + 4 * a1);
        }

        // ---- h-FMA: stripes n=8..23 (k>=256), acc carries x-partials ----
        #pragma unroll 2
        for (int n = 8; n < 24; ++n) {
            const float4 w = packv[wbase + n];
            const int ab = kq8 + 8 * n;
            #pragma unroll
            for (int rr = 0; rr < 8; ++rr) {
                const float4 a = actv[(rbase + rr) * 192 + ab];
                acc[rr] = fmaf(a.x, w.x, acc[rr]);
                acc[rr] = fmaf(a.y, w.y, acc[rr]);
                acc[rr] = fmaf(a.z, w.z, acc[rr]);
                acc[rr] = fmaf(a.w, w.w, acc[rr]);
            }
        }

        // ---- reduce over kq8 (lane bits 0..2) ----
        #pragma unroll
        for (int rr = 0; rr < 8; ++rr) {
            acc[rr] += __shfl_xor(acc[rr], 1, 64);
            acc[rr] += __shfl_xor(acc[rr], 2, 64);
            acc[rr] += __shfl_xor(acc[rr], 4, 64);
        }
        if (kq8 == 0) {
            #pragma unroll
            for (int rr = 0; rr < 8; ++rr) red[col][rbase + rr] = acc[rr];
        }

        // ---- stage x_{t+1} into act x-region (x_t fully consumed) ----
        if (more) {
            const int s0 = tid,       r0 = s0 >> 6, a0 = s0 & 63;
            const int s1 = tid + 512, r1 = s1 >> 6, a1 = s1 & 63;
            ((float4*)&act[0][0])[r0 * 192 + a0] = xr0;
            ((float4*)&act[0][0])[r1 * 192 + a1] = xr1;
        }
        __syncthreads();                         // S1

        // ---- cell update: 16 rows x 8 cells = 128 threads ----
        if (tid < 128) {
            const int r = tid >> 3, m8 = tid & 7;
            float g4[4];
            #pragma unroll
            for (int g = 0; g < 4; ++g)
                g4[g] = red[g * 8 + m8][r] + b4[g];
            const float ig = sigm(g4[0]);
            const float fg = sigm(g4[1]);
            const float gg = fast_tanh(g4[2]);
            const float og = sigm(g4[3]);
            const float cn = fg * c_lds[r][m8] + ig * gg;
            c_lds[r][m8] = cn;
            coh_store_f(out + ((size_t)t * BB + row0 + r) * HH + cell0 + m8,
                        og * fast_tanh(cn));
        }

        // ---- drain h stores, then arrive ----
        asm volatile("s_waitcnt vmcnt(0) lgkmcnt(0)" ::: "memory");
        __syncthreads();                         // S2
        if (more) {
            if (tid == 0)
                __hip_atomic_fetch_add(myctr, 1u, __ATOMIC_RELAXED,
                                       __HIP_MEMORY_SCOPE_AGENT);

            // ---- window: x-partials for t+1 (fills arrive->ready skew) ----
            #pragma unroll
            for (int rr = 0; rr < 8; ++rr) acc[rr] = 0.f;
            #pragma unroll 2
            for (int n = 0; n < 8; ++n) {
                const float4 w = packv[wbase + n];
                const int ab = kq8 + 8 * n;
                #pragma unroll
                for (int rr = 0; rr < 8; ++rr) {
                    const float4 a = actv[(rbase + rr) * 192 + ab];
                    acc[rr] = fmaf(a.x, w.x, acc[rr]);
                    acc[rr] = fmaf(a.y, w.y, acc[rr]);
                    acc[rr] = fmaf(a.z, w.z, acc[rr]);
                    acc[rr] = fmaf(a.w, w.w, acc[rr]);
                }
            }

            // ---- tid0-only spin (R6-proven) ----
            if (tid == 0) {
                const unsigned int target = 64u * (unsigned int)(t + 1);
                while (__hip_atomic_load(myctr, __ATOMIC_RELAXED,
                                         __HIP_MEMORY_SCOPE_AGENT) < target) {
                    __builtin_amdgcn_s_sleep(2);
                }
            }
            __syncthreads();                     // S3

            // ---- load h_t (coherent) -> act h-region, coalesced ----
            {
                const float* hb = out + (size_t)t * BB * HH;
                const int s0 = tid,        r0 = s0 >> 7, a0 = s0 & 127;
                const int s1 = tid + 512,  r1 = s1 >> 7, a1 = s1 & 127;
                const int s2 = tid + 1024, r2 = s2 >> 7, a2 = s2 & 127;
                const int s3 = tid + 1536, r3 = s3 >> 7, a3 = s3 & 127;
                float4 v0, v1, v2, v3;
                coh_load4_f4(hb + (size_t)(row0 + r0) * HH + 4 * a0,
                             hb + (size_t)(row0 + r1) * HH + 4 * a1,
                             hb + (size_t)(row0 + r2) * HH + 4 * a2,
                             hb + (size_t)(row0 + r3) * HH + 4 * a3,
                             v0, v1, v2, v3);
                ((float4*)&act[0][0])[r0 * 192 + 64 + a0] = v0;
                ((float4*)&act[0][0])[r1 * 192 + 64 + a1] = v1;
                ((float4*)&act[0][0])[r2 * 192 + 64 + a2] = v2;
                ((float4*)&act[0][0])[r3 * 192 + 64 + a3] = v3;
            }
            __syncthreads();                     // S4
        }
    }
}

extern "C" void kernel_launch(void* const* d_in, const int* in_sizes, int n_in,
                              void* d_out, int out_size, void* d_ws, size_t ws_size,
                              hipStream_t stream) {
    const float* x  = (const float*)d_in[0];
    const float* Wi = (const float*)d_in[1];
    const float* Wh = (const float*)d_in[2];
    const float* bi = (const float*)d_in[3];
    const float* bh = (const float*)d_in[4];
    const float* h0 = (const float*)d_in[5];
    const float* c0 = (const float*)d_in[6];
    float* out = (float*)d_out;
    unsigned int* ctr = (unsigned int*)d_ws;   // 256 uints

    init_ctr<<<1, 256, 0, stream>>>(ctr);

    void* args[] = { (void*)&x, (void*)&Wi, (void*)&Wh, (void*)&bi,
                     (void*)&bh, (void*)&h0, (void*)&c0, (void*)&out,
                     (void*)&ctr };
    hipError_t e = hipLaunchCooperativeKernel((const void*)lstm_persist,
                                              dim3(NRG * NCG), dim3(THREADS),
                                              args, 0, stream);
    if (e != hipSuccess) {
        (void)hipGetLastError();
        lstm_persist<<<dim3(NRG * NCG), dim3(THREADS), 0, stream>>>(
            x, Wi, Wh, bi, bh, h0, c0, out, ctr);
    }
}

// Round 13
// 4524.017 us; speedup vs baseline: 6.1655x; 1.5615x over previous
//
#include <hip/hip_runtime.h>
#include <math.h>

// LSTM forward: T=1024, B=64, I=256, H=512 (4H=2048), fp32 in/out.
// Round 13: MFMA (16x16x32 bf16) with bf16-SPLIT for fp32 accuracy.
//   Per block: C[16 rows x 32 gate cols] += A[16 x 768] * W[768 x 32].
//   a = ah + al (bf16 hi + bf16 of residual); w likewise. 3 MFMA passes
//   (AhBh, AhBl, AlBh); omitted AlBl ~2^-18 rel -> fp32-level accuracy.
//   * W fragments pre-packed ONCE in LDS in per-lane b128 order (96 KB)
//   * A (x|h) fragments converted per step by all 512 threads (~50 VALU)
//   * wave (n2,k4) = one 16x16 C tile, K-chunk 192 -> 18 MFMA/wave/step
//   * k4-partial reduce via red[8][64][4] using m89-verified C/D layout:
//     col = lane&15, row = (lane>>4)*4 + reg
//   * A/B input layout (std CDNA): row(col) = lane&15, k = (lane>>4)*8 + e
//   * sync skeleton = R12 verbatim (sc0/sc1 IF$ exchange, vmcnt drain,
//     tid0-only spin, x-window pipeline, 4 barriers/step)
// block = (rg: 16 rows) x (cg: 8 cells); 4 x 64 = 256 blocks x 512 thr.

#define TT      1024
#define BB      64
#define II      256
#define HH      512
#define G4H     2048
#define RPB     16
#define NRG     4
#define NCG     64
#define THREADS 512

typedef short  bf16x8 __attribute__((ext_vector_type(8)));
typedef float  f32x4  __attribute__((ext_vector_type(4)));

__device__ __forceinline__ unsigned int cvtpk_bf16(float a, float b) {
    unsigned int r;
    asm volatile("v_cvt_pk_bf16_f32 %0, %1, %2" : "=v"(r) : "v"(a), "v"(b));
    return r;   // lo16 = bf16(a), hi16 = bf16(b), RNE
}

__device__ __forceinline__ void coh_load4_f4(const float* p0, const float* p1,
                                             const float* p2, const float* p3,
                                             float4& a, float4& b,
                                             float4& c, float4& d) {
    asm volatile(
        "global_load_dwordx4 %0, %4, off sc0 sc1\n\t"
        "global_load_dwordx4 %1, %5, off sc0 sc1\n\t"
        "global_load_dwordx4 %2, %6, off sc0 sc1\n\t"
        "global_load_dwordx4 %3, %7, off sc0 sc1\n\t"
        "s_waitcnt vmcnt(0)"
        : "=&v"(a), "=&v"(b), "=&v"(c), "=&v"(d)
        : "v"(p0), "v"(p1), "v"(p2), "v"(p3)
        : "memory");
}
__device__ __forceinline__ void coh_store_f(float* p, float v) {
    asm volatile("global_store_dword %0, %1, off sc0 sc1"
                 :: "v"(p), "v"(v) : "memory");
}
__device__ __forceinline__ float fast_tanh(float v) {
    const float e = __expf(-2.0f * fabsf(v));
    const float r = (1.0f - e) / (1.0f + e);
    return v < 0.0f ? -r : r;
}
__device__ __forceinline__ float sigm(float v) {
    return 1.0f / (1.0f + __expf(-v));
}

// convert f4 (4 consecutive k of row r) into A-fragment hi/lo slots
__device__ __forceinline__ void stage_a(bf16x8* FH, bf16x8* FL,
                                        int kk, int r, int sub, float4 v) {
    const int lane_s = r + 16 * (sub >> 3);     // A: row=lane&15, kgrp=lane>>4
    const int ui     = (sub & 7) >> 1;          // u32 slot 0 or 2
    const unsigned int h0 = cvtpk_bf16(v.x, v.y);
    const unsigned int h1 = cvtpk_bf16(v.z, v.w);
    const float ax = __uint_as_float(h0 << 16);
    const float ay = __uint_as_float(h0 & 0xffff0000u);
    const float az = __uint_as_float(h1 << 16);
    const float aw = __uint_as_float(h1 & 0xffff0000u);
    const unsigned int l0 = cvtpk_bf16(v.x - ax, v.y - ay);
    const unsigned int l1 = cvtpk_bf16(v.z - az, v.w - aw);
    unsigned int* ph = (unsigned int*)&FH[kk * 64 + lane_s];
    unsigned int* pl = (unsigned int*)&FL[kk * 64 + lane_s];
    ph[ui] = h0; ph[ui + 1] = h1;
    pl[ui] = l0; pl[ui + 1] = l1;
}

__global__ void init_ctr(unsigned int* ctr) { ctr[threadIdx.x] = 0; }

__global__ __launch_bounds__(THREADS) void lstm_persist(
    const float* __restrict__ x,    // [T][B][I]
    const float* __restrict__ Wi,   // [I][4H]
    const float* __restrict__ Wh,   // [H][4H]
    const float* __restrict__ bi,   // [4H]
    const float* __restrict__ bh,   // [4H]
    const float* __restrict__ h0p,  // [B][H]
    const float* __restrict__ c0p,  // [B][H]
    float* __restrict__ out,        // [T][B][H]
    unsigned int* __restrict__ ctr) // [NRG*32], pre-zeroed
{
    const int tid   = threadIdx.x;
    const int cg    = blockIdx.x & 63;
    const int rg    = blockIdx.x >> 6;
    const int row0  = rg * RPB;
    const int cell0 = cg * 8;
    const int wv    = tid >> 6;
    const int lane  = tid & 63;
    const int n2    = wv >> 2;            // N-tile (cols 16*n2..)
    const int k4    = wv & 3;             // K-chunk

    __shared__ bf16x8 aFH[24 * 64];       // 24,576 B  A hi frags (kk 0..23)
    __shared__ bf16x8 aFL[24 * 64];       // 24,576 B  A lo
    __shared__ bf16x8 bFH[48 * 64];       // 49,152 B  B hi (n2*24+kk)
    __shared__ bf16x8 bFL[48 * 64];       // 49,152 B  B lo
    __shared__ float  red[8 * 64 * 4];    //  8,192 B  per-wave C partials
    __shared__ float  c_lds[RPB][8];      //    512 B  (total 156,160 B)

    // ---- one-time: pack W fragments (hi/lo) into LDS ----
    for (int i = 0; i < 24; ++i) {
        const int u     = tid + THREADS * i;   // u32 index 0..12287
        const int upos  = u & 3;
        const int slice = u >> 2;              // (nn*24+kk)*64 + lane_
        const int lane_ = slice & 63;
        const int kk    = (slice >> 6) % 24;
        const int nn    = (slice >> 6) / 24;
        const int e0    = upos * 2;
        const int k     = kk * 32 + (lane_ >> 4) * 8 + e0;  // B: k=(lane>>4)*8+e
        const int col   = nn * 16 + (lane_ & 15);           // B: col=lane&15
        const int J     = (col >> 3) * HH + cell0 + (col & 7);
        const float w0  = (k < II) ? Wi[(size_t)k * G4H + J]
                                   : Wh[(size_t)(k - II) * G4H + J];
        const float w1  = (k < II) ? Wi[(size_t)(k + 1) * G4H + J]
                                   : Wh[(size_t)(k + 1 - II) * G4H + J];
        const unsigned int hi = cvtpk_bf16(w0, w1);
        const float f0 = __uint_as_float(hi << 16);
        const float f1 = __uint_as_float(hi & 0xffff0000u);
        const unsigned int lo = cvtpk_bf16(w0 - f0, w1 - f1);
        ((unsigned int*)bFH)[u] = hi;
        ((unsigned int*)bFL)[u] = lo;
    }

    // ---- update-role constants (threads 0..127) ----
    float b4[4];
    if (tid < 128) {
        const int r = tid >> 3, m8 = tid & 7;
        #pragma unroll
        for (int g = 0; g < 4; ++g)
            b4[g] = bi[g * HH + cell0 + m8] + bh[g * HH + cell0 + m8];
        c_lds[r][m8] = c0p[(size_t)(row0 + r) * HH + cell0 + m8];
    }

    // ---- prologue: stage x_0 and h0 fragments ----
    #pragma unroll
    for (int i = 0; i < 2; ++i) {
        const int s = tid + THREADS * i, r = s >> 6, k = 4 * (s & 63);
        const float4 v = *(const float4*)(x + (size_t)(row0 + r) * II + k);
        stage_a(aFH, aFL, k >> 5, r, k & 31, v);
    }
    #pragma unroll
    for (int i = 0; i < 4; ++i) {
        const int s = tid + THREADS * i, r = s >> 7, k = 4 * (s & 127);
        const float4 v = *(const float4*)(h0p + (size_t)(row0 + r) * HH + k);
        stage_a(aFH, aFL, 8 + (k >> 5), r, k & 31, v);
    }
    __syncthreads();

    // ---- x-MFMA for t=0 (kk = k4*2 + {0,1}) ----
    f32x4 acc = {0.f, 0.f, 0.f, 0.f};
    #pragma unroll
    for (int q = 0; q < 2; ++q) {
        const int kk = k4 * 2 + q;
        const bf16x8 ah = aFH[kk * 64 + lane];
        const bf16x8 al = aFL[kk * 64 + lane];
        const bf16x8 wh = bFH[(n2 * 24 + kk) * 64 + lane];
        const bf16x8 wl = bFL[(n2 * 24 + kk) * 64 + lane];
        acc = __builtin_amdgcn_mfma_f32_16x16x32_bf16(ah, wh, acc, 0, 0, 0);
        acc = __builtin_amdgcn_mfma_f32_16x16x32_bf16(ah, wl, acc, 0, 0, 0);
        acc = __builtin_amdgcn_mfma_f32_16x16x32_bf16(al, wh, acc, 0, 0, 0);
    }

    unsigned int* myctr = ctr + rg * 32;

    for (int t = 0; t < TT; ++t) {
        const bool more = (t + 1 < TT);

        // ---- issue x_{t+1} loads early (plain; hidden under h-MFMA) ----
        float4 xr0, xr1;
        int xk0, xr0r, xk1, xr1r;
        if (more) {
            const int s0 = tid;       xr0r = s0 >> 6; xk0 = 4 * (s0 & 63);
            const int s1 = tid + 512; xr1r = s1 >> 6; xk1 = 4 * (s1 & 63);
            xr0 = *(const float4*)(x + ((size_t)(t + 1) * BB + row0 + xr0r) * II + xk0);
            xr1 = *(const float4*)(x + ((size_t)(t + 1) * BB + row0 + xr1r) * II + xk1);
        }

        // ---- h-MFMA (kk = 8 + k4*4 + q), acc carries x part ----
        #pragma unroll
        for (int q = 0; q < 4; ++q) {
            const int kk = 8 + k4 * 4 + q;
            const bf16x8 ah = aFH[kk * 64 + lane];
            const bf16x8 al = aFL[kk * 64 + lane];
            const bf16x8 wh = bFH[(n2 * 24 + kk) * 64 + lane];
            const bf16x8 wl = bFL[(n2 * 24 + kk) * 64 + lane];
            acc = __builtin_amdgcn_mfma_f32_16x16x32_bf16(ah, wh, acc, 0, 0, 0);
            acc = __builtin_amdgcn_mfma_f32_16x16x32_bf16(ah, wl, acc, 0, 0, 0);
            acc = __builtin_amdgcn_mfma_f32_16x16x32_bf16(al, wh, acc, 0, 0, 0);
        }

        // ---- publish C partial; stage x_{t+1} fragments ----
        ((f32x4*)red)[wv * 64 + lane] = acc;
        if (more) {
            stage_a(aFH, aFL, xk0 >> 5, xr0r, xk0 & 31, xr0);
            stage_a(aFH, aFL, xk1 >> 5, xr1r, xk1 & 31, xr1);
        }
        __syncthreads();                        // S1

        // ---- cell update (threads 0..127): m89 C/D layout gather ----
        if (tid < 128) {
            const int r = tid >> 3, m8 = tid & 7;
            const int lane_c_base = 16 * (r >> 2);
            const int reg = r & 3;
            float g4[4];
            #pragma unroll
            for (int g = 0; g < 4; ++g) {
                const int col = g * 8 + m8;
                const int nn  = col >> 4, cl = col & 15;
                const int lc  = cl + lane_c_base;
                float s = b4[g];
                #pragma unroll
                for (int p = 0; p < 4; ++p)
                    s += red[((nn * 4 + p) * 64 + lc) * 4 + reg];
                g4[g] = s;
            }
            const float ig = sigm(g4[0]);
            const float fg = sigm(g4[1]);
            const float gg = fast_tanh(g4[2]);
            const float og = sigm(g4[3]);
            const float cn = fg * c_lds[r][m8] + ig * gg;
            c_lds[r][m8] = cn;
            coh_store_f(out + ((size_t)t * BB + row0 + r) * HH + cell0 + m8,
                        og * fast_tanh(cn));
        }

        // ---- drain h stores, then arrive ----
        asm volatile("s_waitcnt vmcnt(0) lgkmcnt(0)" ::: "memory");
        __syncthreads();                        // S2
        if (more) {
            if (tid == 0)
                __hip_atomic_fetch_add(myctr, 1u, __ATOMIC_RELAXED,
                                       __HIP_MEMORY_SCOPE_AGENT);

            // ---- window: x-MFMA for t+1 ----
            acc = (f32x4){0.f, 0.f, 0.f, 0.f};
            #pragma unroll
            for (int q = 0; q < 2; ++q) {
                const int kk = k4 * 2 + q;
                const bf16x8 ah = aFH[kk * 64 + lane];
                const bf16x8 al = aFL[kk * 64 + lane];
                const bf16x8 wh = bFH[(n2 * 24 + kk) * 64 + lane];
                const bf16x8 wl = bFL[(n2 * 24 + kk) * 64 + lane];
                acc = __builtin_amdgcn_mfma_f32_16x16x32_bf16(ah, wh, acc, 0, 0, 0);
                acc = __builtin_amdgcn_mfma_f32_16x16x32_bf16(ah, wl, acc, 0, 0, 0);
                acc = __builtin_amdgcn_mfma_f32_16x16x32_bf16(al, wh, acc, 0, 0, 0);
            }

            // ---- tid0-only spin (R6-proven) ----
            if (tid == 0) {
                const unsigned int target = 64u * (unsigned int)(t + 1);
                while (__hip_atomic_load(myctr, __ATOMIC_RELAXED,
                                         __HIP_MEMORY_SCOPE_AGENT) < target) {
                    __builtin_amdgcn_s_sleep(2);
                }
            }
            __syncthreads();                    // S3

            // ---- load h_t (coherent) -> A fragments kk 8..23 ----
            {
                const float* hb = out + (size_t)t * BB * HH;
                const int s0 = tid,        r0 = s0 >> 7, k0 = 4 * (s0 & 127);
                const int s1 = tid + 512,  r1 = s1 >> 7, k1 = 4 * (s1 & 127);
                const int s2 = tid + 1024, r2 = s2 >> 7, k2 = 4 * (s2 & 127);
                const int s3 = tid + 1536, r3 = s3 >> 7, k3 = 4 * (s3 & 127);
                float4 v0, v1, v2, v3;
                coh_load4_f4(hb + (size_t)(row0 + r0) * HH + k0,
                             hb + (size_t)(row0 + r1) * HH + k1,
                             hb + (size_t)(row0 + r2) * HH + k2,
                             hb + (size_t)(row0 + r3) * HH + k3,
                             v0, v1, v2, v3);
                stage_a(aFH, aFL, 8 + (k0 >> 5), r0, k0 & 31, v0);
                stage_a(aFH, aFL, 8 + (k1 >> 5), r1, k1 & 31, v1);
                stage_a(aFH, aFL, 8 + (k2 >> 5), r2, k2 & 31, v2);
                stage_a(aFH, aFL, 8 + (k3 >> 5), r3, k3 & 31, v3);
            }
            __syncthreads();                    // S4
        }
    }
}

extern "C" void kernel_launch(void* const* d_in, const int* in_sizes, int n_in,
                              void* d_out, int out_size, void* d_ws, size_t ws_size,
                              hipStream_t stream) {
    const float* x  = (const float*)d_in[0];
    const float* Wi = (const float*)d_in[1];
    const float* Wh = (const float*)d_in[2];
    const float* bi = (const float*)d_in[3];
    const float* bh = (const float*)d_in[4];
    const float* h0 = (const float*)d_in[5];
    const float* c0 = (const float*)d_in[6];
    float* out = (float*)d_out;
    unsigned int* ctr = (unsigned int*)d_ws;   // 256 uints

    init_ctr<<<1, 256, 0, stream>>>(ctr);

    void* args[] = { (void*)&x, (void*)&Wi, (void*)&Wh, (void*)&bi,
                     (void*)&bh, (void*)&h0, (void*)&c0, (void*)&out,
                     (void*)&ctr };
    hipError_t e = hipLaunchCooperativeKernel((const void*)lstm_persist,
                                              dim3(NRG * NCG), dim3(THREADS),
                                              args, 0, stream);
    if (e != hipSuccess) {
        (void)hipGetLastError();
        lstm_persist<<<dim3(NRG * NCG), dim3(THREADS), 0, stream>>>(
            x, Wi, Wh, bi, bh, h0, c0, out, ctr);
    }
}

// Round 14
// 4105.240 us; speedup vs baseline: 6.7945x; 1.1020x over previous
//
#include <hip/hip_runtime.h>
#include <math.h>

// LSTM forward: T=1024, B=64, I=256, H=512 (4H=2048), fp32 in/out.
// Round 14: R13 (bf16-split MFMA, verified) with the LDS bottleneck cut:
//   * staging remap: thread tid writes FRAGMENT tid -> linear b128 LDS
//     writes, zero bank conflicts (R13's lane_s-stride-16 pattern was a
//     structural 16-way conflict: 9.7e8 conflict-cycles measured)
//   * W fragments in REGISTERS (48 VGPR/thread, loaded once): halves the
//     per-step ds_read_b128 count and deletes the 96KB LDS W-pack
//   * everything else verbatim from R13: 3-pass bf16-split (AhBh+AhBl+AlBh),
//     m89 C/D gather, sc0/sc1 IF$ exchange, vmcnt drain, tid0 spin,
//     x_{t+1} window pipeline, 4 barriers/step
// block = (rg: 16 rows) x (cg: 8 cells); 4 x 64 = 256 blocks x 512 thr.

#define TT      1024
#define BB      64
#define II      256
#define HH      512
#define G4H     2048
#define RPB     16
#define NRG     4
#define NCG     64
#define THREADS 512

typedef short  bf16x8 __attribute__((ext_vector_type(8)));
typedef float  f32x4  __attribute__((ext_vector_type(4)));

__device__ __forceinline__ unsigned int cvtpk_bf16(float a, float b) {
    unsigned int r;
    asm volatile("v_cvt_pk_bf16_f32 %0, %1, %2" : "=v"(r) : "v"(a), "v"(b));
    return r;   // lo16 = bf16(a), hi16 = bf16(b), RNE
}

__device__ __forceinline__ void coh_load4_f4(const float* p0, const float* p1,
                                             const float* p2, const float* p3,
                                             float4& a, float4& b,
                                             float4& c, float4& d) {
    asm volatile(
        "global_load_dwordx4 %0, %4, off sc0 sc1\n\t"
        "global_load_dwordx4 %1, %5, off sc0 sc1\n\t"
        "global_load_dwordx4 %2, %6, off sc0 sc1\n\t"
        "global_load_dwordx4 %3, %7, off sc0 sc1\n\t"
        "s_waitcnt vmcnt(0)"
        : "=&v"(a), "=&v"(b), "=&v"(c), "=&v"(d)
        : "v"(p0), "v"(p1), "v"(p2), "v"(p3)
        : "memory");
}
__device__ __forceinline__ void coh_store_f(float* p, float v) {
    asm volatile("global_store_dword %0, %1, off sc0 sc1"
                 :: "v"(p), "v"(v) : "memory");
}
__device__ __forceinline__ float fast_tanh(float v) {
    const float e = __expf(-2.0f * fabsf(v));
    const float r = (1.0f - e) / (1.0f + e);
    return v < 0.0f ? -r : r;
}
__device__ __forceinline__ float sigm(float v) {
    return 1.0f / (1.0f + __expf(-v));
}

// convert 8 consecutive k-elements (v0 = e0..3, v1 = e4..7) of one fragment
// into hi/lo bf16x8; word u = (e2u lo16, e2u+1 hi16)  [R13-verified order]
__device__ __forceinline__ void cvt_frag(float4 v0, float4 v1,
                                         uint4& hi, uint4& lo) {
    hi.x = cvtpk_bf16(v0.x, v0.y);
    hi.y = cvtpk_bf16(v0.z, v0.w);
    hi.z = cvtpk_bf16(v1.x, v1.y);
    hi.w = cvtpk_bf16(v1.z, v1.w);
    lo.x = cvtpk_bf16(v0.x - __uint_as_float(hi.x << 16),
                      v0.y - __uint_as_float(hi.x & 0xffff0000u));
    lo.y = cvtpk_bf16(v0.z - __uint_as_float(hi.y << 16),
                      v0.w - __uint_as_float(hi.y & 0xffff0000u));
    lo.z = cvtpk_bf16(v1.x - __uint_as_float(hi.z << 16),
                      v1.y - __uint_as_float(hi.z & 0xffff0000u));
    lo.w = cvtpk_bf16(v1.z - __uint_as_float(hi.w << 16),
                      v1.w - __uint_as_float(hi.w & 0xffff0000u));
}

__global__ void init_ctr(unsigned int* ctr) { ctr[threadIdx.x] = 0; }

__global__ __launch_bounds__(THREADS) void lstm_persist(
    const float* __restrict__ x,    // [T][B][I]
    const float* __restrict__ Wi,   // [I][4H]
    const float* __restrict__ Wh,   // [H][4H]
    const float* __restrict__ bi,   // [4H]
    const float* __restrict__ bh,   // [4H]
    const float* __restrict__ h0p,  // [B][H]
    const float* __restrict__ c0p,  // [B][H]
    float* __restrict__ out,        // [T][B][H]
    unsigned int* __restrict__ ctr) // [NRG*32], pre-zeroed
{
    const int tid   = threadIdx.x;
    const int cg    = blockIdx.x & 63;
    const int rg    = blockIdx.x >> 6;
    const int row0  = rg * RPB;
    const int cell0 = cg * 8;
    const int wv    = tid >> 6;
    const int lane  = tid & 63;
    const int n2    = wv >> 2;            // N-tile (cols 16*n2..)
    const int k4    = wv & 3;             // K-chunk

    __shared__ uint4 aFH[24 * 64];        // 24,576 B  A hi frags (kk 0..23)
    __shared__ uint4 aFL[24 * 64];        // 24,576 B  A lo
    __shared__ float red[8 * 64 * 4];     //  8,192 B  per-wave C partials
    __shared__ float c_lds[RPB][8];       //    512 B  (total 57,856 B)

    // staging geometry (thread tid <-> fragment):
    //   x frag f (0..511):  kk = f>>6, ls = f&63, r = ls&15,
    //                       kb = kk*32 + (ls>>4)*8    [k in x-space 0..255]
    //   h frags f, f+512:   kk = 8+(f>>6) and 16+(f>>6), same ls ->
    //                       same row, cols kb and kb+256 [h-space 0..511]
    const int s_ls = tid & 63;
    const int s_r  = s_ls & 15;
    const int s_kb = (tid >> 6) * 32 + ((s_ls >> 4) & 3) * 8;

    // ---- one-time: W fragments -> REGISTERS (6 kk slots x hi/lo) ----
    // B-frag: col = n2*16 + (lane&15), k = kk*32 + (lane>>4)*8 + e
    bf16x8 wH[6], wL[6];
    {
        const int col = n2 * 16 + (lane & 15);
        const int J   = (col >> 3) * HH + cell0 + (col & 7);
        #pragma unroll
        for (int s = 0; s < 6; ++s) {
            const int kk = (s < 2) ? (k4 * 2 + s) : (8 + k4 * 4 + (s - 2));
            const int kb = kk * 32 + (lane >> 4) * 8;
            float w[8];
            #pragma unroll
            for (int e = 0; e < 8; ++e) {
                const int k = kb + e;
                w[e] = (k < II) ? Wi[(size_t)k * G4H + J]
                                : Wh[(size_t)(k - II) * G4H + J];
            }
            uint4 hi, lo;
            cvt_frag(make_float4(w[0], w[1], w[2], w[3]),
                     make_float4(w[4], w[5], w[6], w[7]), hi, lo);
            wH[s] = *(bf16x8*)&hi;
            wL[s] = *(bf16x8*)&lo;
        }
    }

    // ---- update-role constants (threads 0..127) ----
    float b4[4];
    if (tid < 128) {
        const int r = tid >> 3, m8 = tid & 7;
        #pragma unroll
        for (int g = 0; g < 4; ++g)
            b4[g] = bi[g * HH + cell0 + m8] + bh[g * HH + cell0 + m8];
        c_lds[r][m8] = c0p[(size_t)(row0 + r) * HH + cell0 + m8];
    }

    // ---- prologue: stage x_0 (frag tid) and h0 (frags tid, tid+512) ----
    {
        const float* xr = x + (size_t)(row0 + s_r) * II + s_kb;
        uint4 hi, lo;
        cvt_frag(*(const float4*)xr, *(const float4*)(xr + 4), hi, lo);
        aFH[tid] = hi; aFL[tid] = lo;

        const float* hr = h0p + (size_t)(row0 + s_r) * HH + s_kb;
        cvt_frag(*(const float4*)hr, *(const float4*)(hr + 4), hi, lo);
        aFH[512 + tid] = hi; aFL[512 + tid] = lo;
        cvt_frag(*(const float4*)(hr + 256), *(const float4*)(hr + 260), hi, lo);
        aFH[1024 + tid] = hi; aFL[1024 + tid] = lo;
    }
    __syncthreads();

    // ---- x-MFMA for t=0 (slots 0,1 = kk k4*2+q) ----
    f32x4 acc = {0.f, 0.f, 0.f, 0.f};
    #pragma unroll
    for (int q = 0; q < 2; ++q) {
        const int kk = k4 * 2 + q;
        const bf16x8 ah = *(const bf16x8*)&aFH[kk * 64 + lane];
        const bf16x8 al = *(const bf16x8*)&aFL[kk * 64 + lane];
        acc = __builtin_amdgcn_mfma_f32_16x16x32_bf16(ah, wH[q], acc, 0, 0, 0);
        acc = __builtin_amdgcn_mfma_f32_16x16x32_bf16(ah, wL[q], acc, 0, 0, 0);
        acc = __builtin_amdgcn_mfma_f32_16x16x32_bf16(al, wH[q], acc, 0, 0, 0);
    }

    unsigned int* myctr = ctr + rg * 32;

    for (int t = 0; t < TT; ++t) {
        const bool more = (t + 1 < TT);

        // ---- issue x_{t+1} loads early (plain; hidden under h-MFMA) ----
        float4 xv0, xv1;
        if (more) {
            const float* xr = x + ((size_t)(t + 1) * BB + row0 + s_r) * II + s_kb;
            xv0 = *(const float4*)xr;
            xv1 = *(const float4*)(xr + 4);
        }

        // ---- h-MFMA (slots 2..5 = kk 8+k4*4+q), acc carries x part ----
        #pragma unroll
        for (int q = 0; q < 4; ++q) {
            const int kk = 8 + k4 * 4 + q;
            const bf16x8 ah = *(const bf16x8*)&aFH[kk * 64 + lane];
            const bf16x8 al = *(const bf16x8*)&aFL[kk * 64 + lane];
            acc = __builtin_amdgcn_mfma_f32_16x16x32_bf16(ah, wH[2 + q], acc, 0, 0, 0);
            acc = __builtin_amdgcn_mfma_f32_16x16x32_bf16(ah, wL[2 + q], acc, 0, 0, 0);
            acc = __builtin_amdgcn_mfma_f32_16x16x32_bf16(al, wH[2 + q], acc, 0, 0, 0);
        }

        // ---- publish C partial; stage x_{t+1} (linear frag write) ----
        ((f32x4*)red)[wv * 64 + lane] = acc;
        if (more) {
            uint4 hi, lo;
            cvt_frag(xv0, xv1, hi, lo);
            aFH[tid] = hi; aFL[tid] = lo;
        }
        __syncthreads();                        // S1

        // ---- cell update (threads 0..127): m89 C/D layout gather ----
        if (tid < 128) {
            const int r = tid >> 3, m8 = tid & 7;
            const int lane_c_base = 16 * (r >> 2);
            const int reg = r & 3;
            float g4[4];
            #pragma unroll
            for (int g = 0; g < 4; ++g) {
                const int col = g * 8 + m8;
                const int nn  = col >> 4, cl = col & 15;
                const int lc  = cl + lane_c_base;
                float s = b4[g];
                #pragma unroll
                for (int p = 0; p < 4; ++p)
                    s += red[((nn * 4 + p) * 64 + lc) * 4 + reg];
                g4[g] = s;
            }
            const float ig = sigm(g4[0]);
            const float fg = sigm(g4[1]);
            const float gg = fast_tanh(g4[2]);
            const float og = sigm(g4[3]);
            const float cn = fg * c_lds[r][m8] + ig * gg;
            c_lds[r][m8] = cn;
            coh_store_f(out + ((size_t)t * BB + row0 + r) * HH + cell0 + m8,
                        og * fast_tanh(cn));
        }

        // ---- drain h stores, then arrive ----
        asm volatile("s_waitcnt vmcnt(0) lgkmcnt(0)" ::: "memory");
        __syncthreads();                        // S2
        if (more) {
            if (tid == 0)
                __hip_atomic_fetch_add(myctr, 1u, __ATOMIC_RELAXED,
                                       __HIP_MEMORY_SCOPE_AGENT);

            // ---- window: x-MFMA for t+1 ----
            acc = (f32x4){0.f, 0.f, 0.f, 0.f};
            #pragma unroll
            for (int q = 0; q < 2; ++q) {
                const int kk = k4 * 2 + q;
                const bf16x8 ah = *(const bf16x8*)&aFH[kk * 64 + lane];
                const bf16x8 al = *(const bf16x8*)&aFL[kk * 64 + lane];
                acc = __builtin_amdgcn_mfma_f32_16x16x32_bf16(ah, wH[q], acc, 0, 0, 0);
                acc = __builtin_amdgcn_mfma_f32_16x16x32_bf16(ah, wL[q], acc, 0, 0, 0);
                acc = __builtin_amdgcn_mfma_f32_16x16x32_bf16(al, wH[q], acc, 0, 0, 0);
            }

            // ---- tid0-only spin (R6-proven) ----
            if (tid == 0) {
                const unsigned int target = 64u * (unsigned int)(t + 1);
                while (__hip_atomic_load(myctr, __ATOMIC_RELAXED,
                                         __HIP_MEMORY_SCOPE_AGENT) < target) {
                    __builtin_amdgcn_s_sleep(2);
                }
            }
            __syncthreads();                    // S3

            // ---- load h_t (coherent) -> frags tid+512, tid+1024 ----
            {
                const float* hr = out + (size_t)t * BB * HH
                                  + (size_t)(row0 + s_r) * HH + s_kb;
                float4 v0, v1, v2, v3;
                coh_load4_f4(hr, hr + 4, hr + 256, hr + 260, v0, v1, v2, v3);
                uint4 hi, lo;
                cvt_frag(v0, v1, hi, lo);
                aFH[512 + tid] = hi; aFL[512 + tid] = lo;
                cvt_frag(v2, v3, hi, lo);
                aFH[1024 + tid] = hi; aFL[1024 + tid] = lo;
            }
            __syncthreads();                    // S4
        }
    }
}

extern "C" void kernel_launch(void* const* d_in, const int* in_sizes, int n_in,
                              void* d_out, int out_size, void* d_ws, size_t ws_size,
                              hipStream_t stream) {
    const float* x  = (const float*)d_in[0];
    const float* Wi = (const float*)d_in[1];
    const float* Wh = (const float*)d_in[2];
    const float* bi = (const float*)d_in[3];
    const float* bh = (const float*)d_in[4];
    const float* h0 = (const float*)d_in[5];
    const float* c0 = (const float*)d_in[6];
    float* out = (float*)d_out;
    unsigned int* ctr = (unsigned int*)d_ws;   // 256 uints

    init_ctr<<<1, 256, 0, stream>>>(ctr);

    void* args[] = { (void*)&x, (void*)&Wi, (void*)&Wh, (void*)&bi,
                     (void*)&bh, (void*)&h0, (void*)&c0, (void*)&out,
                     (void*)&ctr };
    hipError_t e = hipLaunchCooperativeKernel((const void*)lstm_persist,
                                              dim3(NRG * NCG), dim3(THREADS),
                                              args, 0, stream);
    if (e != hipSuccess) {
        (void)hipGetLastError();
        lstm_persist<<<dim3(NRG * NCG), dim3(THREADS), 0, stream>>>(
            x, Wi, Wh, bi, bh, h0, c0, out, ctr);
    }
}